// Round 18
// baseline (77.821 us; speedup 1.0000x reference)
//
#include <hip/hip_runtime.h>

// Problem geometry: B=8, H=512, W=512, HID=64, T=16.
#define HH 512
#define WW 512
#define WPR 16                    // u32 words per global row
#define RO 16                     // owned rows per block
#define HALO 15                   // T-1 steps of temporal blocking
#define ROWS (RO + 2 * HALO)      // 46 rows staged in LDS
#define OW 8                      // owned words per block (256 cols)
#define TW 10                     // tile words = owned + 1 halo word each side
// Halo-word correctness: dependency cone grows 1 bit/step; clamp garbage in
// the +/-1 halo words never reaches owned bits (verified rounds 2-4,6-17).

// lgkm-only barrier (R10-verbatim, incl. sched_barrier: R17 showed removing
// it does not help): waits only on LDS ops; float stores stay in flight.
#define STEP_BARRIER() do {                                   \
    asm volatile("s_waitcnt lgkmcnt(0)" ::: "memory");        \
    __builtin_amdgcn_s_barrier();                             \
    __builtin_amdgcn_sched_barrier(0);                        \
} while (0)

// ---------------------------------------------------------------------------
// Kernel 1 (R10-verbatim, verified absmax 0): out[0]=f0; bit-pack field;
// blocks 0..63 build the 64K-entry quad-LUT (idx16 = 4-bit col-windows of
// rows l-1..l+2 -> 4 bits: cells (2j,2j+1) of rows l and l+1), 8 entries/u32,
// 32 KiB total.
// ---------------------------------------------------------------------------
__global__ __launch_bounds__(512) void init_pack(const float* __restrict__ f0,
                                                 const float* __restrict__ W1,
                                                 const float* __restrict__ b1,
                                                 const float* __restrict__ W2,
                                                 const float* __restrict__ b2,
                                                 int hid,
                                                 float* __restrict__ out,
                                                 unsigned long long* __restrict__ field,
                                                 unsigned int* __restrict__ lut16g) {
    __shared__ unsigned int rule[512];
    const int tid = threadIdx.x;
    int c = blockIdx.x * 512 + tid;
    float v = f0[c];
    out[c] = v;
    unsigned long long m = __ballot(v > 0.5f);
    if ((tid & 63) == 0) field[c >> 6] = m;

    if (blockIdx.x < 64) {
        {   // rule table — byte-identical math to the verified build.
            int p = tid;  // 0..511
            float logit = b2[0];
            for (int k = 0; k < hid; ++k) {
                float a = b1[k];
#pragma unroll
                for (int nn = 0; nn < 9; ++nn)
                    if (p & (1 << nn)) a += W1[nn * hid + k];
                logit += fmaxf(a, 0.0f) * W2[k];
            }
            rule[p] = (logit > 0.0f) ? 1u : 0u;
        }
        __syncthreads();
        if (tid < 128) {   // this block's 128-word slice of the quad-LUT
            int word = blockIdx.x * 128 + tid;
            unsigned int wv = 0;
#pragma unroll
            for (int k = 0; k < 8; ++k) {
                unsigned int e = (unsigned int)word * 8u + k;
                unsigned int a = e & 15u, b = (e >> 4) & 15u;
                unsigned int cc = (e >> 8) & 15u, d = (e >> 12) & 15u;
                unsigned int bit0 = rule[(a & 7u) | ((b & 7u) << 3) | ((cc & 7u) << 6)];
                unsigned int bit1 = rule[((a >> 1) & 7u) | (((b >> 1) & 7u) << 3) | (((cc >> 1) & 7u) << 6)];
                unsigned int bit2 = rule[(b & 7u) | ((cc & 7u) << 3) | ((d & 7u) << 6)];
                unsigned int bit3 = rule[((b >> 1) & 7u) | (((cc >> 1) & 7u) << 3) | (((d >> 1) & 7u) << 6)];
                wv |= (bit0 | (bit1 << 1) | (bit2 << 2) | (bit3 << 3)) << (4 * k);
            }
            lut16g[word] = wv;
        }
    }
}

// ---------------------------------------------------------------------------
// Kernel 2 (R10 geometry: 512 blocks = 8 images x 32 row-groups x 2 col-
// groups, 512 thr). Intra-block producer/consumer split per step:
//   waves 0-3 (tid<256): compute step t into newb (R10-verbatim quad-LUT
//                        pair tasks; npairs*10 <= 220 < 256).
//   waves 4-7 (tid>=256): emit frame t-1 from oldb (stable: both partitions
//                        only READ oldb this step; the end-of-step barrier
//                        orders these reads before step t+1 overwrites it).
// ONE lgkm-only barrier per step. Frame 15 emitted by all threads post-loop.
// ---------------------------------------------------------------------------
__global__ __launch_bounds__(512) void mega(const unsigned int* __restrict__ field,
                                            const unsigned int* __restrict__ lut16g,
                                            float* __restrict__ out,
                                            int n, int T) {
    __shared__ alignas(16) unsigned int lut16[8192];   // 32 KiB
    __shared__ unsigned int bufA[ROWS * TW];
    __shared__ unsigned int bufB[ROWS * TW];

    const int tid = threadIdx.x;
    const int cg = blockIdx.x & 1;
    const int rg = (blockIdx.x >> 1) & 31;
    const int b  = blockIdx.x >> 6;
    const int r0 = rg * RO;          // first owned global row
    const int q0 = cg * OW;          // first owned global word
    const int c0 = cg * (OW * 32);   // first owned global column

    // quad-LUT: 2048 uint4 loads (coalesced; L2-broadcast across blocks).
    for (int i = tid; i < 2048; i += 512)
        ((uint4*)lut16)[i] = ((const uint4*)lut16g)[i];
    // bit tile load (wrap in H via &511, in W via &15) — verified R3/R8/R10.
    {
        const unsigned int* F = field + b * (HH * WPR);
        for (int i = tid; i < ROWS * TW; i += 512) {
            int l = i / TW, tw = i - l * TW;
            int g  = (r0 - HALO + l) & (HH - 1);
            int gw = (q0 - 1 + tw) & (WPR - 1);
            bufA[i] = F[g * WPR + gw];
        }
    }
    __syncthreads();

    unsigned int* oldb = bufA;
    unsigned int* newb = bufB;
    float* outb = out + (size_t)b * (HH * WW);

    for (int t = 1; t < T; ++t) {
        if (tid < 256) {
            // ---- compute partition (R10-verbatim math) ----
            const int npairs = 23 - t;           // pairs tile rows [t, 46-t)
            if (tid < npairs * TW) {
                const int pr = tid / TW;
                const int w  = tid - pr * TW;
                const int l  = t + 2 * pr;       // first output row
                const unsigned int* Ra = oldb + (l - 1) * TW;
                const unsigned int* Rb = oldb + l * TW;
                const unsigned int* Rc = oldb + (l + 1) * TW;
                const unsigned int* Rd = oldb + (l + 2) * TW;
                const int wl = (w == 0) ? 0 : w - 1;    // garbage-safe (cone)
                const int wn = (w == TW - 1) ? TW - 1 : w + 1;
                unsigned long long ea = ((((unsigned long long)Ra[wn] << 32) | Ra[w]) << 1) | (Ra[wl] >> 31);
                unsigned long long eb = ((((unsigned long long)Rb[wn] << 32) | Rb[w]) << 1) | (Rb[wl] >> 31);
                unsigned long long ec = ((((unsigned long long)Rc[wn] << 32) | Rc[w]) << 1) | (Rc[wl] >> 31);
                unsigned long long ed = ((((unsigned long long)Rd[wn] << 32) | Rd[w]) << 1) | (Rd[wl] >> 31);
                unsigned int owb = 0, owc = 0;
#pragma unroll
                for (int j = 0; j < 16; ++j) {
                    unsigned int idx = (unsigned int)((ea >> (2 * j)) & 15ull)
                                     | ((unsigned int)((eb >> (2 * j)) & 15ull) << 4)
                                     | ((unsigned int)((ec >> (2 * j)) & 15ull) << 8)
                                     | ((unsigned int)((ed >> (2 * j)) & 15ull) << 12);
                    unsigned int ent = (lut16[idx >> 3] >> ((idx & 7u) * 4)) & 15u;
                    owb |= (ent & 3u) << (2 * j);
                    owc |= ((ent >> 2) & 3u) << (2 * j);
                }
                newb[l * TW + w] = owb;
                newb[(l + 1) * TW + w] = owc;
            }
        } else if (t >= 2) {
            // ---- emit partition: frame t-1 from oldb (read-only) ----
            // 256 threads x 16 cells: lr = e>>4, 16-col group g = e&15.
            const int e  = tid - 256;
            const int lr = e >> 4;
            const int g  = e & 15;
            const int col = g * 16;
            unsigned int wd = oldb[(HALO + lr) * TW + 1 + (g >> 1)];
            unsigned int bits = (wd >> ((g & 1) * 16)) & 0xFFFFu;
            float* dst = outb + (size_t)(t - 1) * n + (size_t)(r0 + lr) * WW + c0 + col;
#pragma unroll
            for (int q = 0; q < 4; ++q) {
                unsigned int nib = (bits >> (4 * q)) & 15u;
                float4 v;
                v.x = (float)(nib & 1u);
                v.y = (float)((nib >> 1) & 1u);
                v.z = (float)((nib >> 2) & 1u);
                v.w = (float)(nib >> 3);
                *(float4*)(dst + 4 * q) = v;
            }
        }
        STEP_BARRIER();    // orders: newb complete; ALL reads of oldb done
                           // (compute windows + emit) before oldb is reused.
        unsigned int* tmp = oldb; oldb = newb; newb = tmp;
    }

    // final frame (t = T-1 = 15) from oldb (post-swap), all 512 threads,
    // R10-verbatim 2x float4 pattern; threads are barrier-synced above.
    {
        float* outt = outb + (size_t)(T - 1) * n;
#pragma unroll
        for (int rep = 0; rep < 2; ++rep) {
            int cell = (rep * 512 + tid) * 4;           // 0..4092, step 4
            int lr  = cell >> 8;                        // owned row 0..15
            int col = cell & 255;                       // owned col
            unsigned int wv = oldb[(HALO + lr) * TW + 1 + (col >> 5)];
            unsigned int nib = (wv >> (col & 31)) & 15u;
            float4 v;
            v.x = (float)(nib & 1u);
            v.y = (float)((nib >> 1) & 1u);
            v.z = (float)((nib >> 2) & 1u);
            v.w = (float)(nib >> 3);
            *(float4*)(outt + (size_t)(r0 + lr) * WW + c0 + col) = v;
        }
    }
}

// ---------------------------------------------------------------------------
// Launch: init_pack -> mega (2 dispatches).
// d_ws: [0, 32768)            quad-LUT (8192 u32)
//       [32768, 32768 + n/8)  packed step-0 bit field (256 KiB)
// ---------------------------------------------------------------------------
extern "C" void kernel_launch(void* const* d_in, const int* in_sizes, int n_in,
                              void* d_out, int out_size, void* d_ws, size_t ws_size,
                              hipStream_t stream) {
    const float* f0 = (const float*)d_in[0];
    const float* W1 = (const float*)d_in[1];
    const float* b1 = (const float*)d_in[2];
    const float* W2 = (const float*)d_in[3];
    const float* b2 = (const float*)d_in[4];
    float* out = (float*)d_out;

    const int n = in_sizes[0];        // B*1*H*W = 2,097,152
    const int hid = in_sizes[2];      // 64
    const int T = out_size / n;       // 16
    const int B = n / (HH * WW);      // 8

    char* ws = (char*)d_ws;
    unsigned int* lut16g = (unsigned int*)ws;
    unsigned long long* fld = (unsigned long long*)(ws + 32768);

    init_pack<<<n / 512, 512, 0, stream>>>(f0, W1, b1, W2, b2, hid, out, fld, lut16g);
    mega<<<B * (HH / RO) * 2, 512, 0, stream>>>((const unsigned int*)fld, lut16g,
                                                out, n, T);
}